// Round 9
// baseline (37.362 us; speedup 1.0000x reference)
//
#include <hip/hip_runtime.h>

// DGT forward, collapsed to a binary-tree descent on sign(pred_z[node]).
// Structure (= R8): 8-lane groups (8 samples/wave), f32 fast-path dot with
// 3-step DPP group reduce; rare f64 recompute when |z_f32| < EPS_TIE (the
// only region where the f32 sign can disagree with the f64 numpy reference).
//
// Hard-learned rules (R1..R8):
//  - The 2nd __launch_bounds__ arg PINS waves/EU to exactly N on this
//    toolchain (measured occupancy = N/8: R3 hint3->37.5%, R1 hint4->50%,
//    R8 hint2->25%), and VGPR cap = 256/N (spill past it: R5/R6/R7).
//  - Perf law: dur ~ 1/(chains-in-flight per SIMD) = waves/SIMD x
//    samples/wave (R1 16 chains=39us, R8 16 chains=37us).
//  - This round: hint 2->3. Cap 85 vs R8's 76-VGPR footprint -> no spill;
//    24 chains/SIMD. Spill signature to watch: WRITE_SIZE must stay 8.2MB.
//  - ALL per-thread state in NAMED float4s (runtime-indexed arrays go to
//    scratch, R2/R4).
//
// Shapes: x [65536,256] f32, W_pred [1023,256], b_pred [1023],
//         W_or [16,1024], action_stds [16,1024].
// d_out = [out (65536x16) | std (65536x16)] f32.

#define BATCH   65536
#define IN_DIM  256
#define NLEVEL  10
#define NLEAF   1024
#define OUT_DIM 16
#define EPS_TIE 1e-3f

#define DPP_QUAD_XOR1   0xB1   // quad_perm [1,0,3,2]  : lane ^1
#define DPP_QUAD_XOR2   0x4E   // quad_perm [2,3,0,1]  : lane ^2
#define DPP_HALF_MIRROR 0x141  // row_half_mirror      : lane l <-> 7-l

template <int CTRL>
__device__ __forceinline__ float dpp_xfer(float v) {
    return __int_as_float(__builtin_amdgcn_update_dpp(
        0, __float_as_int(v), CTRL, 0xf, 0xf, true));
}

// Sum across the 8-lane group; bitwise-identical on all 8 lanes
// (involution pairing + commutative add at every step).
__device__ __forceinline__ float group8_sum(float v) {
    v += dpp_xfer<DPP_QUAD_XOR1>(v);
    v += dpp_xfer<DPP_QUAD_XOR2>(v);
    v += dpp_xfer<DPP_HALF_MIRROR>(v);
    return v;
}
__device__ __forceinline__ float group8_max(float v) {
    v = fmaxf(v, dpp_xfer<DPP_QUAD_XOR1>(v));
    v = fmaxf(v, dpp_xfer<DPP_QUAD_XOR2>(v));
    v = fmaxf(v, dpp_xfer<DPP_HALF_MIRROR>(v));
    return v;
}

// Rare exact-sign fallback (|z_f32| < EPS_TIE). Group-uniform entry: z is
// bitwise-uniform across the 8-lane group, so shuffle partners are active.
__device__ __forceinline__ int tree_sign_f64(
    float4 x0, float4 x1, float4 x2, float4 x3,
    float4 x4, float4 x5, float4 x6, float4 x7,
    const float* wrow, float bias, int l)
{
    double A0 = 0.0, A1 = 0.0, A2 = 0.0, A3 = 0.0;
#define ACC64(K, XV)                                                        \
    {                                                                       \
        float4 w = *reinterpret_cast<const float4*>(wrow + (K)*32 + l * 4); \
        A0 += (double)XV.x * (double)w.x; A1 += (double)XV.y * (double)w.y; \
        A2 += (double)XV.z * (double)w.z; A3 += (double)XV.w * (double)w.w; \
    }
    ACC64(0, x0) ACC64(1, x1) ACC64(2, x2) ACC64(3, x3)
    ACC64(4, x4) ACC64(5, x5) ACC64(6, x6) ACC64(7, x7)
#undef ACC64
    double Z = (A0 + A1) + (A2 + A3);
    #pragma unroll
    for (int off = 4; off > 0; off >>= 1)   // xor involution: uniform result
        Z += __shfl_xor(Z, off, 64);
    Z += (double)bias;
    return (Z < 0.0) ? 1 : 0;
}

// 256 threads = 4 waves; 8 samples/wave -> 32/block, 2048 blocks.
__global__ __launch_bounds__(256, 3) void dgt_kernel(
    const float* __restrict__ x,
    const float* __restrict__ W_pred,
    const float* __restrict__ b_pred,
    const float* __restrict__ W_or,
    const float* __restrict__ a_std,
    float* __restrict__ out)
{
    const int lane = threadIdx.x & 63;
    const int wid  = threadIdx.x >> 6;   // wave in block (0..3)
    const int l    = lane & 7;           // lane within 8-group
    const int g    = lane >> 3;          // group (sample) within wave
    const int sample = blockIdx.x * 32 + wid * 8 + g;

    // x fragment: elem k*32 + l*4 + c; 128B coalesced segments per group.
    const float* xrow = x + (size_t)sample * IN_DIM;
    float4 x0 = *reinterpret_cast<const float4*>(xrow +   0 + l * 4);
    float4 x1 = *reinterpret_cast<const float4*>(xrow +  32 + l * 4);
    float4 x2 = *reinterpret_cast<const float4*>(xrow +  64 + l * 4);
    float4 x3 = *reinterpret_cast<const float4*>(xrow +  96 + l * 4);
    float4 x4 = *reinterpret_cast<const float4*>(xrow + 128 + l * 4);
    float4 x5 = *reinterpret_cast<const float4*>(xrow + 160 + l * 4);
    float4 x6 = *reinterpret_cast<const float4*>(xrow + 192 + l * 4);
    float4 x7 = *reinterpret_cast<const float4*>(xrow + 224 + l * 4);

    int node = 0, pos = 0;
    float bcur = b_pred[0];
    const float* wrow = W_pred;

    #pragma unroll
    for (int lvl = 0; lvl < NLEVEL; ++lvl) {
        // All 8 row-fragment loads issued up front: one vmcnt covers them.
        float4 w0 = *reinterpret_cast<const float4*>(wrow +   0 + l * 4);
        float4 w1 = *reinterpret_cast<const float4*>(wrow +  32 + l * 4);
        float4 w2 = *reinterpret_cast<const float4*>(wrow +  64 + l * 4);
        float4 w3 = *reinterpret_cast<const float4*>(wrow +  96 + l * 4);
        float4 w4 = *reinterpret_cast<const float4*>(wrow + 128 + l * 4);
        float4 w5 = *reinterpret_cast<const float4*>(wrow + 160 + l * 4);
        float4 w6 = *reinterpret_cast<const float4*>(wrow + 192 + l * 4);
        float4 w7 = *reinterpret_cast<const float4*>(wrow + 224 + l * 4);

        // Children biases fetched before the sign resolves (off crit path).
        float bL = 0.f, bR = 0.f;
        if (lvl < NLEVEL - 1) {
            bL = b_pred[2 * node + 1];
            bR = b_pred[2 * node + 2];
        }

        // 4 independent partials (8-deep dependent FMA chains each).
        float a0, a1, a2, a3;
        a0  = x0.x * w0.x; a1  = x0.y * w0.y; a2  = x0.z * w0.z; a3  = x0.w * w0.w;
        a0 += x1.x * w1.x; a1 += x1.y * w1.y; a2 += x1.z * w1.z; a3 += x1.w * w1.w;
        a0 += x2.x * w2.x; a1 += x2.y * w2.y; a2 += x2.z * w2.z; a3 += x2.w * w2.w;
        a0 += x3.x * w3.x; a1 += x3.y * w3.y; a2 += x3.z * w3.z; a3 += x3.w * w3.w;
        a0 += x4.x * w4.x; a1 += x4.y * w4.y; a2 += x4.z * w4.z; a3 += x4.w * w4.w;
        a0 += x5.x * w5.x; a1 += x5.y * w5.y; a2 += x5.z * w5.z; a3 += x5.w * w5.w;
        a0 += x6.x * w6.x; a1 += x6.y * w6.y; a2 += x6.z * w6.z; a3 += x6.w * w6.w;
        a0 += x7.x * w7.x; a1 += x7.y * w7.y; a2 += x7.z * w7.z; a3 += x7.w * w7.w;
        float z = group8_sum((a0 + a1) + (a2 + a3)) + bcur;

        int right;
        if (__builtin_expect(fabsf(z) >= EPS_TIE, 1))
            right = (z < 0.f) ? 1 : 0;
        else
            right = tree_sign_f64(x0, x1, x2, x3, x4, x5, x6, x7,
                                  wrow, bcur, l);   // group-uniform entry

        pos  = 2 * pos + right;
        node = 2 * node + 1 + right;
        if (lvl < NLEVEL - 1) {
            bcur = right ? bR : bL;
            wrow = W_pred + (size_t)node * IN_DIM;
        }
    }
    const int leaf = pos;  // in [0, 1024)

    // Epilogue: lane l covers classes {2l, 2l+1}; tables are L2-resident.
    float zx = W_or[(size_t)(2 * l)     * NLEAF + leaf];
    float zy = W_or[(size_t)(2 * l + 1) * NLEAF + leaf];
    float m  = group8_max(fmaxf(zx, zy));
    float ex = __expf(zx - m), ey = __expf(zy - m);
    float s  = group8_sum(ex + ey);
    // Per wave: addresses (base+g)*64B + l*8B -> contiguous 512B.
    *reinterpret_cast<float2*>(out + (size_t)sample * OUT_DIM + 2 * l) =
        make_float2(ex / s, ey / s);

    float dx = a_std[(size_t)(2 * l)     * NLEAF + leaf];
    float dy = a_std[(size_t)(2 * l + 1) * NLEAF + leaf];
    *reinterpret_cast<float2*>(out + (size_t)BATCH * OUT_DIM
                               + (size_t)sample * OUT_DIM + 2 * l) =
        make_float2(fminf(fmaxf(dx, -20.f), 2.f),
                    fminf(fmaxf(dy, -20.f), 2.f));
}

extern "C" void kernel_launch(void* const* d_in, const int* in_sizes, int n_in,
                              void* d_out, int out_size, void* d_ws, size_t ws_size,
                              hipStream_t stream) {
    const float* x      = (const float*)d_in[0];
    const float* W_pred = (const float*)d_in[1];
    const float* b_pred = (const float*)d_in[2];
    const float* W_or   = (const float*)d_in[3];
    const float* a_std  = (const float*)d_in[4];
    float* out = (float*)d_out;

    hipLaunchKernelGGL(dgt_kernel, dim3(BATCH / 32), dim3(256), 0, stream,
                       x, W_pred, b_pred, W_or, a_std, out);
}